// Round 6
// baseline (8507.264 us; speedup 1.0000x reference)
//
#include <hip/hip_runtime.h>
#include <hip/hip_bf16.h>
#include <stdint.h>

// 2-layer LSTM, B=1024 T=80 E=100 U=512, bf16 MFMA path.
// R1: layer2(t-1) || layer1(t) software pipeline.
// R3: K-loop depth-3 prefetch, 4-buffer LDS ring, counted vmcnt.
// R4: 128x128 output tile -> 1778us (bytes-bound confirmed).
// R5: persistent + grid barrier: REGRESSED 10ms (acquire-inv per spin poll).
// R6: sc0|sc1-bypass H path: 2011us. Correct but kills ALL L2 reuse (FETCH 745MB).
// R7: cached loads everywhere + ONE release(wbl2)/acquire(inv) fence pair per
//     iteration (hoisted out of the spin), plain H stores, and bm-colocating
//     swizzle (blockIdx%8 = bm) so both roles' blocks sharing an activation
//     panel sit on one XCD: post-inv refetch ~12MB/iter from L3 vs 48MB bypass.
//     Correctness does NOT depend on the %8->XCD heuristic (fences do it).

#define B_ 1024
#define T_ 80
#define NBLK 256

using bf16 = __hip_bfloat16;
typedef __attribute__((ext_vector_type(8))) short short8;
typedef __attribute__((ext_vector_type(4))) float f32x4;
typedef __attribute__((ext_vector_type(4))) unsigned short ushort4v;

__device__ __forceinline__ float sigf(float x) { return 1.f / (1.f + __expf(-x)); }
__device__ __forceinline__ float tanh_f(float x) { return 2.f / (1.f + __expf(-2.f * x)) - 1.f; }

typedef const __attribute__((address_space(1))) void* gp1_t;
typedef __attribute__((address_space(3))) void* lp3_t;
__device__ __forceinline__ void llds16(const void* g, void* l) {
  __builtin_amdgcn_global_load_lds((gp1_t)g, (lp3_t)l, 16, 0, 0);
}

// XP[t][b][e] (e padded to 128 with zeros), bf16
__global__ void embed_kernel(const int* __restrict__ tokens, const float* __restrict__ emb,
                             bf16* __restrict__ XP) {
  int idx = blockIdx.x * 256 + threadIdx.x;  // over T_*B_*128
  int e = idx & 127;
  int bt = idx >> 7;
  int b = bt & (B_ - 1);
  int t = bt >> 10;
  if (t >= T_) return;
  int tok = tokens[b * T_ + t];
  float v = (e < 100) ? emb[tok * 100 + e] : 0.f;
  XP[idx] = __float2bfloat16(v);
}

// W [Kreal][2048] fp32 -> WT [2048][Kp] bf16, coalesced both ways via 32x32 LDS tile
__global__ void transpose_kernel(const float* __restrict__ W, bf16* __restrict__ WT,
                                 int Kreal, int Kp) {
  __shared__ float tile[32][33];
  int tn = blockIdx.x * 32;
  int tk = blockIdx.y * 32;
  int lx = threadIdx.x & 31;
  int ly = threadIdx.x >> 5;  // 8
#pragma unroll
  for (int r = ly; r < 32; r += 8) {
    int k = tk + r;
    tile[r][lx] = (k < Kreal) ? W[(size_t)k * 2048 + tn + lx] : 0.f;
  }
  __syncthreads();
#pragma unroll
  for (int r = ly; r < 32; r += 8) {
    WT[(size_t)(tn + r) * Kp + tk + lx] = __float2bfloat16(tile[lx][r]);
  }
}

// grid barrier: monotonic counter, no reset -> no ABA. Release = __threadfence()
// (wbl2: dirty H lines reach the coherence point) BEFORE the add; spin is RELAXED
// (no per-poll cache ops -- the R5 bug); acquire = __threadfence() (inv) ONCE after
// the spin exits, clustered across all blocks right at barrier exit.
__device__ __forceinline__ void grid_barrier(unsigned* cnt, unsigned target) {
  __threadfence();   // release: writeback dirty L2 (all threads, idempotent)
  __syncthreads();
  if (threadIdx.x == 0) {
    __hip_atomic_fetch_add(cnt, 1u, __ATOMIC_RELAXED, __HIP_MEMORY_SCOPE_AGENT);
    while (__hip_atomic_load(cnt, __ATOMIC_RELAXED, __HIP_MEMORY_SCOPE_AGENT) < target)
      __builtin_amdgcn_s_sleep(2);
  }
  __syncthreads();
  __threadfence();   // acquire: one inv -> subsequent cached reads are fresh
}

// Persistent dual-role cell kernel. Decode: bm = blockIdx%8 (XCD-colocated under
// the %8 heuristic: all blocks sharing a 128-row activation panel on one XCD),
// s = blockIdx/8, role = s>>4 (0=layer1 t=it, 1=layer2 t=it-1), g = s&15.
// Block tile 128 rows x 32 units; 8 waves (2m x 4n); wave = 4x2 16x16x32 frags.
// LDS: 4 x 16KB staging ring; epilogue reuses as 64x133 f32 z-tile (2 passes).
// C cell-state: creg[pass][4] per thread (fp32).
__global__ __launch_bounds__(512, 2) void lstm_persist(
    const bf16* __restrict__ XP, const bf16* __restrict__ W1T, const bf16* __restrict__ U1T,
    const bf16* __restrict__ W2T, const bf16* __restrict__ U2T,
    const float* __restrict__ b1, const float* __restrict__ b2,
    bf16* __restrict__ H1, bf16* __restrict__ H2, unsigned* bar) {
  __shared__ alignas(16) char smem[65536];
  const int bm = blockIdx.x & 7;        // row-panel, colocated per XCD
  const int s = blockIdx.x >> 3;
  const int role = s >> 4;              // 0 = layer1, 1 = layer2
  const int g = s & 15;                 // unit-group
  const int u0 = g * 32;
  const int tid = threadIdx.x;
  const int w = tid >> 6, l = tid & 63, q = l >> 4, m = l & 15;
  const int wm = w >> 2, wn = w & 3;

  const bf16* B0 = role ? W2T : W1T;
  const bf16* B1 = role ? U2T : U1T;
  const int ldb0 = role ? 512 : 128;
  const int lda0 = role ? 512 : 128;
  const int nkt0 = role ? 16 : 4;
  const int total = nkt0 + 16;
  const float* bias = role ? b2 : b1;

  // B staging rows fixed for the whole sequence (cached)
  const int brow_n = (w >> 1) * 512 + u0 + (w & 1) * 16 + m;
  const bf16* brow0 = B0 + (size_t)brow_n * ldb0;
  const bf16* brow1 = B1 + (size_t)brow_n * 512;
  const int arow_r = bm * 128 + w * 16 + m;  // A row this wave stages
  const int fbase = q * 256 + m * 16;

  // epilogue constants + persistent cell state
  const int erow = tid >> 3;     // 0..63
  const int ub = (tid & 7) * 4;  // unit within group
  float bi[4], bff[4], bg[4], bo[4];
#pragma unroll
  for (int j = 0; j < 4; ++j) {
    int gu = u0 + ub + j;
    bi[j] = bias[gu];
    bff[j] = bias[512 + gu];
    bg[j] = bias[1024 + gu];
    bo[j] = bias[1536 + gu];
  }
  float creg[2][4] = {{0.f, 0.f, 0.f, 0.f}, {0.f, 0.f, 0.f, 0.f}};

  for (int it = 0; it <= T_; ++it) {
    const bool active = role ? (it >= 1) : (it < T_);
    if (active) {
      const int t = role ? it - 1 : it;
      const bf16* A0 = role ? (H1 + (size_t)((t + 1) & 1) * 524288)
                            : (XP + (size_t)t * 131072);
      const bf16* A1 = role ? (H2 + (size_t)(t & 1) * 524288)
                            : (H1 + (size_t)(t & 1) * 524288);
      bf16* Hout = role ? (H2 + (size_t)((t + 1) & 1) * 524288)
                        : (H1 + (size_t)((t + 1) & 1) * 524288);
      const bf16* arow0 = A0 + (size_t)arow_r * lda0;
      const bf16* arow1 = A1 + (size_t)arow_r * 512;

      auto stage = [&](int kt, int buf) {
        const bf16 *ga, *gb;
        if (kt < nkt0) { int k0 = kt * 32 + q * 8; ga = arow0 + k0; gb = brow0 + k0; }
        else { int k0 = (kt - nkt0) * 32 + q * 8; ga = arow1 + k0; gb = brow1 + k0; }
        char* base = smem + buf * 16384 + w * 1024;
        llds16(ga, base);          // A (cached; fresh after the per-iter inv)
        llds16(gb, base + 8192);   // B weights (cached, L3->L2 after inv)
      };

      f32x4 acc[4][2];
#pragma unroll
      for (int mi = 0; mi < 4; ++mi)
#pragma unroll
        for (int nj = 0; nj < 2; ++nj) acc[mi][nj] = (f32x4){0.f, 0.f, 0.f, 0.f};

      stage(0, 0);
      stage(1, 1);
      stage(2, 2);
      for (int kt = 0; kt < total; ++kt) {
        const int rem = total - 1 - kt;
        if (rem >= 2)      asm volatile("s_waitcnt vmcnt(4)" ::: "memory");
        else if (rem == 1) asm volatile("s_waitcnt vmcnt(2)" ::: "memory");
        else               asm volatile("s_waitcnt vmcnt(0)" ::: "memory");
        __builtin_amdgcn_s_barrier();
        if (kt + 3 < total) stage(kt + 3, (kt + 3) & 3);
        const int cb = (kt & 3) * 16384;
        short8 a[4], b[2];
#pragma unroll
        for (int mi = 0; mi < 4; ++mi)
          a[mi] = *(const short8*)(smem + cb + (wm * 4 + mi) * 1024 + fbase);
#pragma unroll
        for (int nj = 0; nj < 2; ++nj)
          b[nj] = *(const short8*)(smem + cb + 8192 + (wn * 2 + nj) * 1024 + fbase);
#pragma unroll
        for (int mi = 0; mi < 4; ++mi)
#pragma unroll
          for (int nj = 0; nj < 2; ++nj)
            acc[mi][nj] = __builtin_amdgcn_mfma_f32_16x16x32_bf16(a[mi], b[nj], acc[mi][nj], 0, 0, 0);
      }

      __syncthreads();
      float* zs = (float*)smem;  // [64][133]
#pragma unroll
      for (int pass = 0; pass < 2; ++pass) {
        if (pass) __syncthreads();
        if (wm == pass) {
#pragma unroll
          for (int mi = 0; mi < 4; ++mi)
#pragma unroll
            for (int nj = 0; nj < 2; ++nj)
#pragma unroll
              for (int r = 0; r < 4; ++r)
                zs[(mi * 16 + q * 4 + r) * 133 + wn * 32 + nj * 16 + m] = acc[mi][nj][r];
        }
        __syncthreads();
        int grow = bm * 128 + pass * 64 + erow;
        size_t gi = (size_t)grow * 512 + u0 + ub;
        unsigned short hv[4];
#pragma unroll
        for (int j = 0; j < 4; ++j) {
          float zi = zs[erow * 133 + ub + j] + bi[j];
          float zf = zs[erow * 133 + 32 + ub + j] + bff[j];
          float zg = zs[erow * 133 + 64 + ub + j] + bg[j];
          float zo = zs[erow * 133 + 96 + ub + j] + bo[j];
          float c = sigf(zf) * creg[pass][j] + sigf(zi) * tanh_f(zg);
          float h = sigf(zo) * tanh_f(c);
          creg[pass][j] = c;
          bf16 hb = __float2bfloat16(h);
          hv[j] = *(unsigned short*)&hb;
        }
        *(ushort4v*)(Hout + gi) = (ushort4v){hv[0], hv[1], hv[2], hv[3]};
      }
    }
    grid_barrier(bar, (unsigned)(NBLK * (it + 1)));
  }
}

// out[b] = sigmoid(h2[b,:] @ Wout + bout); one wave per row
__global__ void output_kernel(const bf16* __restrict__ H2, const float* __restrict__ Wout,
                              const float* __restrict__ bout, float* __restrict__ out) {
  int w = threadIdx.x >> 6, l = threadIdx.x & 63;
  int row = blockIdx.x * 4 + w;
  const bf16* h = H2 + (size_t)row * 512;
  float s = 0.f;
#pragma unroll
  for (int k = 0; k < 8; ++k) {
    int kk = l + k * 64;
    s += __bfloat162float(h[kk]) * Wout[kk];
  }
#pragma unroll
  for (int off = 32; off > 0; off >>= 1) s += __shfl_down(s, off);
  if (l == 0) out[row] = sigf(s + bout[0]);
}

extern "C" void kernel_launch(void* const* d_in, const int* in_sizes, int n_in,
                              void* d_out, int out_size, void* d_ws, size_t ws_size,
                              hipStream_t stream) {
  const int* tokens = (const int*)d_in[0];
  const float* emb = (const float*)d_in[1];
  const float* W1 = (const float*)d_in[2];
  const float* U1 = (const float*)d_in[3];
  const float* b1 = (const float*)d_in[4];
  const float* W2 = (const float*)d_in[5];
  const float* U2 = (const float*)d_in[6];
  const float* b2 = (const float*)d_in[7];
  const float* Wout = (const float*)d_in[8];
  const float* bout = (const float*)d_in[9];
  float* out = (float*)d_out;
  char* ws = (char*)d_ws;

  const size_t oXP = 0;          // 80*1024*128 bf16 = 20971520
  const size_t oW1T = 20971520;  // 2048*128 bf16
  const size_t oU1T = 21495808;  // 2048*512 bf16
  const size_t oW2T = 23592960;
  const size_t oU2T = 25690112;
  const size_t oH1 = 27787264;   // 2 x 1024*512 bf16
  const size_t oH2 = 29884416;
  const size_t oBar = 31981568;  // barrier counter (64B)
  if (ws_size < 36175872) return;

  bf16* XP = (bf16*)(ws + oXP);
  bf16* W1T = (bf16*)(ws + oW1T);
  bf16* U1T = (bf16*)(ws + oU1T);
  bf16* W2T = (bf16*)(ws + oW2T);
  bf16* U2T = (bf16*)(ws + oU2T);
  bf16* H1 = (bf16*)(ws + oH1);
  bf16* H2 = (bf16*)(ws + oH2);
  unsigned* bar = (unsigned*)(ws + oBar);

  hipMemsetAsync(ws + oH1, 0, 1048576, stream);  // H1 buf0
  hipMemsetAsync(ws + oH2, 0, 1048576, stream);  // H2 buf0
  hipMemsetAsync(ws + oBar, 0, 64, stream);      // barrier counter

  embed_kernel<<<40960, 256, 0, stream>>>(tokens, emb, XP);
  transpose_kernel<<<dim3(64, 4), 256, 0, stream>>>(W1, W1T, 100, 128);
  transpose_kernel<<<dim3(64, 16), 256, 0, stream>>>(U1, U1T, 512, 512);
  transpose_kernel<<<dim3(64, 16), 256, 0, stream>>>(W2, W2T, 512, 512);
  transpose_kernel<<<dim3(64, 16), 256, 0, stream>>>(U2, U2T, 512, 512);

  lstm_persist<<<NBLK, 512, 0, stream>>>(XP, W1T, U1T, W2T, U2T, b1, b2, H1, H2, bar);

  // final h2 in buffer (T_&1)==0
  output_kernel<<<256, 256, 0, stream>>>(H2, Wout, bout, out);
}

// Round 7
// 1791.425 us; speedup vs baseline: 4.7489x; 4.7489x over previous
//
#include <hip/hip_runtime.h>
#include <hip/hip_bf16.h>
#include <stdint.h>

// 2-layer LSTM, B=1024 T=80 E=100 U=512, bf16 MFMA path.
// R1: layer2(t-1) || layer1(t) software pipeline (81 launches).
// R2: XCD-colocating tile swizzle (neutral, kept).
// R3: K-loop depth-3 prefetch, 4-buffer LDS ring, counted vmcnt.
// R4: 128x128 output tile -> 1778us (cache-fabric bytes-bound confirmed).
// R5-R7: persistence attempts all regressed (acquire-inv per poll 10ms; sc-bypass
//     2011us; per-iter threadfence 8.5ms). Launch boundaries are the cheapest
//     device-wide coherence. Persistence abandoned; R4 is the base.
// R8: read-ahead register double-buffer in the K-loop: body(kt) = {vm-wait(kt+1),
//     barrier, stage(kt+3), ds_read frags(kt+1) -> spare set, MFMA(kt) from
//     current set}. MFMA no longer waits on this iteration's ds_reads
//     (lgkmcnt(6) keeps them in flight) -> LDS read latency+throughput overlap
//     MFMA instead of serializing with it. total is even -> manual 2x unroll
//     with named register sets (no runtime-indexed frag arrays).

#define B_ 1024
#define T_ 80

using bf16 = __hip_bfloat16;
typedef __attribute__((ext_vector_type(8))) short short8;
typedef __attribute__((ext_vector_type(4))) float f32x4;
typedef __attribute__((ext_vector_type(4))) unsigned short ushort4v;

__device__ __forceinline__ float sigf(float x) { return 1.f / (1.f + __expf(-x)); }
__device__ __forceinline__ float tanh_f(float x) { return 2.f / (1.f + __expf(-2.f * x)) - 1.f; }

typedef const __attribute__((address_space(1))) void* gp1_t;
typedef __attribute__((address_space(3))) void* lp3_t;
__device__ __forceinline__ void llds16(const void* g, void* l) {
  // per-lane global gather -> LDS wave-uniform base + lane*16
  __builtin_amdgcn_global_load_lds((gp1_t)g, (lp3_t)l, 16, 0, 0);
}

// XP[t][b][e] (e padded to 128 with zeros), bf16
__global__ void embed_kernel(const int* __restrict__ tokens, const float* __restrict__ emb,
                             bf16* __restrict__ XP) {
  int idx = blockIdx.x * 256 + threadIdx.x;  // over T_*B_*128
  int e = idx & 127;
  int bt = idx >> 7;
  int b = bt & (B_ - 1);
  int t = bt >> 10;
  if (t >= T_) return;
  int tok = tokens[b * T_ + t];
  float v = (e < 100) ? emb[tok * 100 + e] : 0.f;
  XP[idx] = __float2bfloat16(v);
}

// W [Kreal][2048] fp32 -> WT [2048][Kp] bf16, coalesced both ways via 32x32 LDS tile
__global__ void transpose_kernel(const float* __restrict__ W, bf16* __restrict__ WT,
                                 int Kreal, int Kp) {
  __shared__ float tile[32][33];
  int tn = blockIdx.x * 32;
  int tk = blockIdx.y * 32;
  int lx = threadIdx.x & 31;
  int ly = threadIdx.x >> 5;  // 8
#pragma unroll
  for (int r = ly; r < 32; r += 8) {
    int k = tk + r;
    tile[r][lx] = (k < Kreal) ? W[(size_t)k * 2048 + tn + lx] : 0.f;
  }
  __syncthreads();
#pragma unroll
  for (int r = ly; r < 32; r += 8) {
    WT[(size_t)(tn + r) * Kp + tk + lx] = __float2bfloat16(tile[lx][r]);
  }
}

struct CellParams {
  const bf16* A0; const bf16* B0;
  const bf16* A1; const bf16* B1;
  int lda0, ldb0, nkt0, lda1, ldb1, nkt1;
  const float* bias; float* C; bf16* H;
};

// z = A0@B0^T-seg + A1@B1^T-seg + bias; gates i,f,g,o; C fp32 in-place; H bf16 out.
// Block tile 128 rows x 32 units (128 z-cols). Dual-cell: blocks 0..127 -> p0,
// 128..255 -> p1. 512 threads = 8 waves as 2(m) x 4(n); wave = 4x2 16x16 frags.
// LDS: 4 x (8KB A + 8KB B) staging ring (64 KB); epilogue reuses as 64x133 f32 z.
// K-loop (R8): per body: entry inflight = 2 stages (4 loads) -> vmcnt(2) certifies
// stage(kt+1); barrier (ALL waves' kt+1 landed); stage(kt+3) post-barrier
// (overwrites buf[(kt-1)&3] whose readers completed pre-barrier); ds_read
// frags(kt+1) -> spare regs; MFMA(kt) from current regs (no lgkm dependency).
__global__ __launch_bounds__(512) void cell_kernel(CellParams p0, CellParams p1) {
  __shared__ alignas(16) char smem[65536];
  const CellParams& p = (blockIdx.x >> 7) ? p1 : p0;
  const int lb = blockIdx.x & 127;
  const int g = (lb & 7) | ((lb >> 6) << 3);  // unit-group 0..15 (XCD-colocated: lb%8)
  const int bm = (lb >> 3) & 7;               // 128-row tile 0..7
  const int u0 = g * 32;                      // unit offset
  const int tid = threadIdx.x;
  const int w = tid >> 6, l = tid & 63, q = l >> 4, m = l & 15;
  const int wm = w >> 2, wn = w & 3;

  // staging: wave w stages A rows bm*128 + w*16 + m, and B n-rows for gate w>>1,
  // units u0 + (w&1)*16 + m. Lane l lands at LDS base + l*16 (HW rule).
  const bf16* arow0 = p.A0 + (size_t)(bm * 128 + w * 16 + m) * p.lda0;
  const bf16* brow0 = p.B0 + (size_t)((w >> 1) * 512 + u0 + (w & 1) * 16 + m) * p.ldb0;
  const bf16* arow1 = p.A1 + (size_t)(bm * 128 + w * 16 + m) * p.lda1;
  const bf16* brow1 = p.B1 + (size_t)((w >> 1) * 512 + u0 + (w & 1) * 16 + m) * p.ldb1;

  auto stage = [&](int kt, int buf) {
    const bf16 *ga, *gb;
    if (kt < p.nkt0) { int k0 = kt * 32 + q * 8; ga = arow0 + k0; gb = brow0 + k0; }
    else { int k0 = (kt - p.nkt0) * 32 + q * 8; ga = arow1 + k0; gb = brow1 + k0; }
    char* base = smem + buf * 16384 + w * 1024;
    llds16(ga, base);          // A: [wave-group w][chunk q][m][16B]
    llds16(gb, base + 8192);   // B: same layout, n-rows
  };

  f32x4 acc[4][2];
#pragma unroll
  for (int mi = 0; mi < 4; ++mi)
#pragma unroll
    for (int nj = 0; nj < 2; ++nj) acc[mi][nj] = (f32x4){0.f, 0.f, 0.f, 0.f};

  const int fbase = q * 256 + m * 16;
  const int total = p.nkt0 + p.nkt1;  // 20 (layer1) or 32 (layer2), both EVEN

  auto kbody = [&](int kt, short8 (&ac)[4], short8 (&bc)[2],
                   short8 (&an)[4], short8 (&bn)[2]) {
    const int rem = total - 1 - kt;
    if (rem >= 2) asm volatile("s_waitcnt vmcnt(2)" ::: "memory");
    else          asm volatile("s_waitcnt vmcnt(0)" ::: "memory");
    __builtin_amdgcn_s_barrier();          // ALL waves' stage(kt+1) landed
    __builtin_amdgcn_sched_barrier(0);     // keep ds_reads below the barrier
    if (kt + 3 < total) stage(kt + 3, (kt + 3) & 3);
    const int nb = ((kt + 1) & 3) * 16384;
    // read-ahead: frags(kt+1) into the spare set (overlaps MFMA below);
    // at kt==total-1 this reads stale buf contents -- never consumed.
#pragma unroll
    for (int mi = 0; mi < 4; ++mi)
      an[mi] = *(const short8*)(smem + nb + (wm * 4 + mi) * 1024 + fbase);
#pragma unroll
    for (int nj = 0; nj < 2; ++nj)
      bn[nj] = *(const short8*)(smem + nb + 8192 + (wn * 2 + nj) * 1024 + fbase);
    // MFMA from the current set: no dependency on the reads just issued.
#pragma unroll
    for (int mi = 0; mi < 4; ++mi)
#pragma unroll
      for (int nj = 0; nj < 2; ++nj)
        acc[mi][nj] = __builtin_amdgcn_mfma_f32_16x16x32_bf16(ac[mi], bc[nj], acc[mi][nj], 0, 0, 0);
  };

  short8 aC[4], bC[2], aN[4], bN[2];
  stage(0, 0);
  stage(1, 1);
  stage(2, 2);
  asm volatile("s_waitcnt vmcnt(4)" ::: "memory");  // own stage(0) landed
  __builtin_amdgcn_s_barrier();                     // everyone's stage(0) landed
  __builtin_amdgcn_sched_barrier(0);
#pragma unroll
  for (int mi = 0; mi < 4; ++mi)
    aC[mi] = *(const short8*)(smem + (wm * 4 + mi) * 1024 + fbase);
#pragma unroll
  for (int nj = 0; nj < 2; ++nj)
    bC[nj] = *(const short8*)(smem + 8192 + (wn * 2 + nj) * 1024 + fbase);

  for (int kt = 0; kt < total; kt += 2) {
    kbody(kt, aC, bC, aN, bN);
    kbody(kt + 1, aN, bN, aC, bC);
  }

  __syncthreads();
  float* zs = (float*)smem;  // [64][133] f32 = 34 KB
  const int erow = tid >> 3;        // 0..63
  const int ub = (tid & 7) * 4;     // unit base within group, 0..28
  float bi[4], bff[4], bg[4], bo[4];
#pragma unroll
  for (int j = 0; j < 4; ++j) {
    int gu = u0 + ub + j;
    bi[j] = p.bias[gu];
    bff[j] = p.bias[512 + gu];
    bg[j] = p.bias[1024 + gu];
    bo[j] = p.bias[1536 + gu];
  }
#pragma unroll
  for (int pass = 0; pass < 2; ++pass) {
    if (pass) __syncthreads();  // protect zs while pass-0 reads finish
    if (wm == pass) {
#pragma unroll
      for (int mi = 0; mi < 4; ++mi)
#pragma unroll
        for (int nj = 0; nj < 2; ++nj)
#pragma unroll
          for (int r = 0; r < 4; ++r)
            zs[(mi * 16 + q * 4 + r) * 133 + wn * 32 + nj * 16 + m] = acc[mi][nj][r];
    }
    __syncthreads();
    int grow = bm * 128 + pass * 64 + erow;
    size_t gi = (size_t)grow * 512 + u0 + ub;
    float4 cold = *(const float4*)(p.C + gi);
    float cn[4];
    unsigned short hv[4];
#pragma unroll
    for (int j = 0; j < 4; ++j) {
      float zi = zs[erow * 133 + ub + j] + bi[j];
      float zf = zs[erow * 133 + 32 + ub + j] + bff[j];
      float zg = zs[erow * 133 + 64 + ub + j] + bg[j];
      float zo = zs[erow * 133 + 96 + ub + j] + bo[j];
      float co = (j == 0) ? cold.x : (j == 1) ? cold.y : (j == 2) ? cold.z : cold.w;
      float c = sigf(zf) * co + sigf(zi) * tanh_f(zg);
      float h = sigf(zo) * tanh_f(c);
      cn[j] = c;
      bf16 hb = __float2bfloat16(h);
      hv[j] = *(unsigned short*)&hb;
    }
    *(float4*)(p.C + gi) = make_float4(cn[0], cn[1], cn[2], cn[3]);
    *(ushort4v*)(p.H + gi) = (ushort4v){hv[0], hv[1], hv[2], hv[3]};
  }
}

// out[b] = sigmoid(h2[b,:] @ Wout + bout); one wave per row
__global__ void output_kernel(const bf16* __restrict__ H2, const float* __restrict__ Wout,
                              const float* __restrict__ bout, float* __restrict__ out) {
  int w = threadIdx.x >> 6, l = threadIdx.x & 63;
  int row = blockIdx.x * 4 + w;
  const bf16* h = H2 + (size_t)row * 512;
  float s = 0.f;
#pragma unroll
  for (int k = 0; k < 8; ++k) {
    int kk = l + k * 64;
    s += __bfloat162float(h[kk]) * Wout[kk];
  }
#pragma unroll
  for (int off = 32; off > 0; off >>= 1) s += __shfl_down(s, off);
  if (l == 0) out[row] = sigf(s + bout[0]);
}

extern "C" void kernel_launch(void* const* d_in, const int* in_sizes, int n_in,
                              void* d_out, int out_size, void* d_ws, size_t ws_size,
                              hipStream_t stream) {
  const int* tokens = (const int*)d_in[0];
  const float* emb = (const float*)d_in[1];
  const float* W1 = (const float*)d_in[2];
  const float* U1 = (const float*)d_in[3];
  const float* b1 = (const float*)d_in[4];
  const float* W2 = (const float*)d_in[5];
  const float* U2 = (const float*)d_in[6];
  const float* b2 = (const float*)d_in[7];
  const float* Wout = (const float*)d_in[8];
  const float* bout = (const float*)d_in[9];
  float* out = (float*)d_out;
  char* ws = (char*)d_ws;

  const size_t oXP = 0;          // 80*1024*128 bf16 = 20971520
  const size_t oW1T = 20971520;  // 2048*128 bf16
  const size_t oU1T = 21495808;  // 2048*512 bf16
  const size_t oW2T = 23592960;
  const size_t oU2T = 25690112;
  const size_t oH1 = 27787264;   // 2 x 1024*512 bf16
  const size_t oH2 = 29884416;
  const size_t oC1 = 31981568;   // 1024*512 f32
  const size_t oC2 = 34078720;
  if (ws_size < 36175872) return;

  bf16* XP = (bf16*)(ws + oXP);
  bf16* W1T = (bf16*)(ws + oW1T);
  bf16* U1T = (bf16*)(ws + oU1T);
  bf16* W2T = (bf16*)(ws + oW2T);
  bf16* U2T = (bf16*)(ws + oU2T);
  bf16* H1 = (bf16*)(ws + oH1);
  bf16* H2 = (bf16*)(ws + oH2);
  float* C1 = (float*)(ws + oC1);
  float* C2 = (float*)(ws + oC2);

  hipMemsetAsync(ws + oH1, 0, 1048576, stream);  // H1 buf0
  hipMemsetAsync(ws + oH2, 0, 1048576, stream);  // H2 buf0
  hipMemsetAsync(ws + oC1, 0, 4194304, stream);  // C1 + C2

  embed_kernel<<<40960, 256, 0, stream>>>(tokens, emb, XP);
  transpose_kernel<<<dim3(64, 4), 256, 0, stream>>>(W1, W1T, 100, 128);
  transpose_kernel<<<dim3(64, 16), 256, 0, stream>>>(U1, U1T, 512, 512);
  transpose_kernel<<<dim3(64, 16), 256, 0, stream>>>(W2, W2T, 512, 512);
  transpose_kernel<<<dim3(64, 16), 256, 0, stream>>>(U2, U2T, 512, 512);

  auto mkL1 = [&](int t) {
    CellParams p;
    p.A0 = XP + (size_t)t * 131072; p.B0 = W1T; p.lda0 = 128; p.ldb0 = 128; p.nkt0 = 4;
    p.A1 = H1 + (size_t)(t & 1) * 524288; p.B1 = U1T; p.lda1 = 512; p.ldb1 = 512; p.nkt1 = 16;
    p.bias = b1; p.C = C1; p.H = H1 + (size_t)((t + 1) & 1) * 524288;
    return p;
  };
  auto mkL2 = [&](int t) {
    CellParams p;
    p.A0 = H1 + (size_t)((t + 1) & 1) * 524288; p.B0 = W2T; p.lda0 = 512; p.ldb0 = 512; p.nkt0 = 16;
    p.A1 = H2 + (size_t)(t & 1) * 524288; p.B1 = U2T; p.lda1 = 512; p.ldb1 = 512; p.nkt1 = 16;
    p.bias = b2; p.C = C2; p.H = H2 + (size_t)((t + 1) & 1) * 524288;
    return p;
  };

  cell_kernel<<<128, 512, 0, stream>>>(mkL1(0), mkL1(0));
  for (int k = 1; k < T_; ++k)
    cell_kernel<<<256, 512, 0, stream>>>(mkL2(k - 1), mkL1(k));  // layer2(k-1) || layer1(k)
  cell_kernel<<<128, 512, 0, stream>>>(mkL2(T_ - 1), mkL2(T_ - 1));

  // final h2 in buffer (T_&1)==0
  output_kernel<<<256, 256, 0, stream>>>(H2, Wout, bout, out);
}

// Round 8
// 1765.172 us; speedup vs baseline: 4.8195x; 1.0149x over previous
//
#include <hip/hip_runtime.h>
#include <hip/hip_bf16.h>
#include <stdint.h>

// 2-layer LSTM, B=1024 T=80 E=100 U=512, bf16 MFMA path.
// R1: layer2(t-1) || layer1(t) software pipeline (81 launches).
// R2: XCD-colocating tile swizzle (neutral, kept).
// R3: depth-3 prefetch, 4-buffer LDS ring, counted vmcnt (neutral at 4 blk/CU).
// R4: 128x128 output tile -> 1778us (cache-fabric bytes-bound confirmed).
// R5-R7: persistence attempts regressed (fence/inv semantics); abandoned.
// R8: register read-ahead: neutral -> K-loop not latency-bound.
// R9: halve synchronization. BK=64 (two k-subtiles per stage/barrier): 16/10
//     k-steps instead of 32/20, same bytes, ring = 4x32KB = 128KB LDS.
//     Single-pass epilogue (z[128][132] = 68KB fits now): 2 syncs not 4.
//     Vectorized embed (short8). Targets per-step/per-launch fixed overhead,
//     which the R3/R8 nulls + LDS-floor arithmetic (3.4us vs 19us) implicate.

#define B_ 1024
#define T_ 80

using bf16 = __hip_bfloat16;
typedef __attribute__((ext_vector_type(8))) short short8;
typedef __attribute__((ext_vector_type(4))) float f32x4;
typedef __attribute__((ext_vector_type(8))) unsigned short ushort8v;

__device__ __forceinline__ float sigf(float x) { return 1.f / (1.f + __expf(-x)); }
__device__ __forceinline__ float tanh_f(float x) { return 2.f / (1.f + __expf(-2.f * x)) - 1.f; }

typedef const __attribute__((address_space(1))) void* gp1_t;
typedef __attribute__((address_space(3))) void* lp3_t;
__device__ __forceinline__ void llds16(const void* g, void* l) {
  // per-lane global gather -> LDS wave-uniform base + lane*16
  __builtin_amdgcn_global_load_lds((gp1_t)g, (lp3_t)l, 16, 0, 0);
}

// XP[t][b][e] (e padded to 128 with zeros), bf16. Vectorized: thread = 8 elems.
__global__ void embed_kernel(const int* __restrict__ tokens, const float* __restrict__ emb,
                             bf16* __restrict__ XP) {
  int idx = blockIdx.x * 256 + threadIdx.x;  // over T_*B_*16
  int j = idx & 15;                          // e0 = j*8
  int bt = idx >> 4;
  int b = bt & (B_ - 1);
  int t = bt >> 10;
  if (t >= T_) return;
  int tok = tokens[b * T_ + t];
  int e0 = j * 8;
  float v[8];
  if (e0 + 8 <= 100) {
    *(float4*)(v) = *(const float4*)(emb + (size_t)tok * 100 + e0);
    *(float4*)(v + 4) = *(const float4*)(emb + (size_t)tok * 100 + e0 + 4);
  } else if (e0 < 100) {  // e0 == 96: 4 real + 4 zero
    *(float4*)(v) = *(const float4*)(emb + (size_t)tok * 100 + e0);
    v[4] = v[5] = v[6] = v[7] = 0.f;
  } else {
#pragma unroll
    for (int k = 0; k < 8; ++k) v[k] = 0.f;
  }
  ushort8v o;
#pragma unroll
  for (int k = 0; k < 8; ++k) {
    bf16 hb = __float2bfloat16(v[k]);
    o[k] = *(unsigned short*)&hb;
  }
  *(ushort8v*)(XP + (size_t)bt * 128 + e0) = o;
}

// W [Kreal][2048] fp32 -> WT [2048][Kp] bf16, coalesced both ways via 32x32 LDS tile
__global__ void transpose_kernel(const float* __restrict__ W, bf16* __restrict__ WT,
                                 int Kreal, int Kp) {
  __shared__ float tile[32][33];
  int tn = blockIdx.x * 32;
  int tk = blockIdx.y * 32;
  int lx = threadIdx.x & 31;
  int ly = threadIdx.x >> 5;  // 8
#pragma unroll
  for (int r = ly; r < 32; r += 8) {
    int k = tk + r;
    tile[r][lx] = (k < Kreal) ? W[(size_t)k * 2048 + tn + lx] : 0.f;
  }
  __syncthreads();
#pragma unroll
  for (int r = ly; r < 32; r += 8) {
    WT[(size_t)(tn + r) * Kp + tk + lx] = __float2bfloat16(tile[lx][r]);
  }
}

struct CellParams {
  const bf16* A0; const bf16* B0;
  const bf16* A1; const bf16* B1;
  int lda0, ldb0, nkt0, lda1, ldb1, nkt1;  // nkt in units of BK=64
  const float* bias; float* C; bf16* H;
};

// z = A0@B0^T-seg + A1@B1^T-seg + bias; gates i,f,g,o; C fp32 in-place; H bf16 out.
// Block tile 128 rows x 32 units (128 z-cols). Dual-cell: blocks 0..127 -> p0,
// 128..255 -> p1. 512 threads = 8 waves as 2(m) x 4(n); wave = 4x2 16x16 frags.
// BK=64: per stage, wave w stages its 16 A rows and 16 B n-rows as TWO k-subtiles
// (s=0,1), 4 llds16/wave. LDS buffer layout: A [w][s][q][m][16B] at w*2048+s*1024,
// B same at +16384; 32KB/buffer, 4-buffer ring = 128KB. Frag reads are lane-linear
// (conflict-free). K-loop: wait vmcnt(8) (2 stages in flight), barrier, stage(kt+3),
// read 12 frags, 16 MFMA. Tail peels vmcnt(4)/vmcnt(0).
// Epilogue: single pass via z[128][132] f32 (68KB, reuses ring after syncthreads).
__global__ __launch_bounds__(512, 1) void cell_kernel(CellParams p0, CellParams p1) {
  __shared__ alignas(16) char smem[131072];
  const CellParams& p = (blockIdx.x >> 7) ? p1 : p0;
  const int lb = blockIdx.x & 127;
  const int g = (lb & 7) | ((lb >> 6) << 3);  // unit-group 0..15 (XCD-colocated: lb%8)
  const int bm = (lb >> 3) & 7;               // 128-row tile 0..7
  const int u0 = g * 32;                      // unit offset
  const int tid = threadIdx.x;
  const int w = tid >> 6, l = tid & 63, q = l >> 4, m = l & 15;
  const int wm = w >> 2, wn = w & 3;

  // staging rows: wave w stages A rows bm*128+w*16+m; B n-rows (w>>1)*512+u0+(w&1)*16+m
  const bf16* arow0 = p.A0 + (size_t)(bm * 128 + w * 16 + m) * p.lda0;
  const bf16* brow0 = p.B0 + (size_t)((w >> 1) * 512 + u0 + (w & 1) * 16 + m) * p.ldb0;
  const bf16* arow1 = p.A1 + (size_t)(bm * 128 + w * 16 + m) * p.lda1;
  const bf16* brow1 = p.B1 + (size_t)((w >> 1) * 512 + u0 + (w & 1) * 16 + m) * p.ldb1;

  auto stage = [&](int kt, int buf) {
    const bf16 *ga, *gb;
    if (kt < p.nkt0) { int k0 = kt * 64 + q * 8; ga = arow0 + k0; gb = brow0 + k0; }
    else { int k0 = (kt - p.nkt0) * 64 + q * 8; ga = arow1 + k0; gb = brow1 + k0; }
    char* ab = smem + buf * 32768 + w * 2048;
    llds16(ga, ab);                    // A s=0 (k 0..31 of this BK)
    llds16(ga + 32, ab + 1024);        // A s=1 (k 32..63)
    llds16(gb, ab + 16384);            // B s=0
    llds16(gb + 32, ab + 16384 + 1024);// B s=1
  };

  f32x4 acc[4][2];
#pragma unroll
  for (int mi = 0; mi < 4; ++mi)
#pragma unroll
    for (int nj = 0; nj < 2; ++nj) acc[mi][nj] = (f32x4){0.f, 0.f, 0.f, 0.f};

  const int fbase = q * 256 + m * 16;
  const int total = p.nkt0 + p.nkt1;  // 10 (layer1) or 16 (layer2)

  stage(0, 0);
  stage(1, 1);
  stage(2, 2);
  for (int kt = 0; kt < total; ++kt) {
    const int rem = total - 1 - kt;
    if (rem >= 2)      asm volatile("s_waitcnt vmcnt(8)" ::: "memory");  // stage kt landed
    else if (rem == 1) asm volatile("s_waitcnt vmcnt(4)" ::: "memory");
    else               asm volatile("s_waitcnt vmcnt(0)" ::: "memory");
    __builtin_amdgcn_s_barrier();       // ALL waves' stage(kt) landed
    __builtin_amdgcn_sched_barrier(0);  // keep ds_reads below the barrier
    if (kt + 3 < total) stage(kt + 3, (kt + 3) & 3);
    const int cb = (kt & 3) * 32768;
    short8 a0[4], b0[2], a1[4], b1[2];
#pragma unroll
    for (int mi = 0; mi < 4; ++mi)
      a0[mi] = *(const short8*)(smem + cb + (wm * 4 + mi) * 2048 + fbase);
#pragma unroll
    for (int nj = 0; nj < 2; ++nj)
      b0[nj] = *(const short8*)(smem + cb + 16384 + (wn * 2 + nj) * 2048 + fbase);
#pragma unroll
    for (int mi = 0; mi < 4; ++mi)
      a1[mi] = *(const short8*)(smem + cb + (wm * 4 + mi) * 2048 + 1024 + fbase);
#pragma unroll
    for (int nj = 0; nj < 2; ++nj)
      b1[nj] = *(const short8*)(smem + cb + 16384 + (wn * 2 + nj) * 2048 + 1024 + fbase);
#pragma unroll
    for (int mi = 0; mi < 4; ++mi)
#pragma unroll
      for (int nj = 0; nj < 2; ++nj)
        acc[mi][nj] = __builtin_amdgcn_mfma_f32_16x16x32_bf16(a0[mi], b0[nj], acc[mi][nj], 0, 0, 0);
#pragma unroll
    for (int mi = 0; mi < 4; ++mi)
#pragma unroll
      for (int nj = 0; nj < 2; ++nj)
        acc[mi][nj] = __builtin_amdgcn_mfma_f32_16x16x32_bf16(a1[mi], b1[nj], acc[mi][nj], 0, 0, 0);
  }

  __syncthreads();  // all frag reads done -> safe to overwrite ring with z
  float* zs = (float*)smem;  // [128][132] f32 = 67.6 KB
#pragma unroll
  for (int mi = 0; mi < 4; ++mi)
#pragma unroll
    for (int nj = 0; nj < 2; ++nj)
#pragma unroll
      for (int r = 0; r < 4; ++r)
        zs[(wm * 64 + mi * 16 + q * 4 + r) * 132 + wn * 32 + nj * 16 + m] = acc[mi][nj][r];
  __syncthreads();

  // one thread per (row, 8-unit chunk): 512 threads = 128 rows x 4 chunks
  const int erow = tid >> 2;
  const int ub8 = (tid & 3) * 8;
  const int gu0 = u0 + ub8;
  float bi[8], bfv[8], bg[8], bo[8];
  *(float4*)(bi) = *(const float4*)(p.bias + gu0);
  *(float4*)(bi + 4) = *(const float4*)(p.bias + gu0 + 4);
  *(float4*)(bfv) = *(const float4*)(p.bias + 512 + gu0);
  *(float4*)(bfv + 4) = *(const float4*)(p.bias + 512 + gu0 + 4);
  *(float4*)(bg) = *(const float4*)(p.bias + 1024 + gu0);
  *(float4*)(bg + 4) = *(const float4*)(p.bias + 1024 + gu0 + 4);
  *(float4*)(bo) = *(const float4*)(p.bias + 1536 + gu0);
  *(float4*)(bo + 4) = *(const float4*)(p.bias + 1536 + gu0 + 4);

  float zr[32];
  const float* zrow = zs + erow * 132;
  *(float4*)(zr) = *(const float4*)(zrow + ub8);            // i gate
  *(float4*)(zr + 4) = *(const float4*)(zrow + ub8 + 4);
  *(float4*)(zr + 8) = *(const float4*)(zrow + 32 + ub8);   // f gate
  *(float4*)(zr + 12) = *(const float4*)(zrow + 32 + ub8 + 4);
  *(float4*)(zr + 16) = *(const float4*)(zrow + 64 + ub8);  // g gate
  *(float4*)(zr + 20) = *(const float4*)(zrow + 64 + ub8 + 4);
  *(float4*)(zr + 24) = *(const float4*)(zrow + 96 + ub8);  // o gate
  *(float4*)(zr + 28) = *(const float4*)(zrow + 96 + ub8 + 4);

  const int grow = bm * 128 + erow;
  const size_t gi = (size_t)grow * 512 + gu0;
  float cold[8], cn[8];
  *(float4*)(cold) = *(const float4*)(p.C + gi);
  *(float4*)(cold + 4) = *(const float4*)(p.C + gi + 4);
  unsigned short hv[8];
#pragma unroll
  for (int j = 0; j < 8; ++j) {
    float zi = zr[j] + bi[j];
    float zf = zr[8 + j] + bfv[j];
    float zg = zr[16 + j] + bg[j];
    float zo = zr[24 + j] + bo[j];
    float c = sigf(zf) * cold[j] + sigf(zi) * tanh_f(zg);
    float h = sigf(zo) * tanh_f(c);
    cn[j] = c;
    bf16 hb = __float2bfloat16(h);
    hv[j] = *(unsigned short*)&hb;
  }
  *(float4*)(p.C + gi) = make_float4(cn[0], cn[1], cn[2], cn[3]);
  *(float4*)(p.C + gi + 4) = make_float4(cn[4], cn[5], cn[6], cn[7]);
  *(ushort8v*)(p.H + gi) = (ushort8v){hv[0], hv[1], hv[2], hv[3], hv[4], hv[5], hv[6], hv[7]};
}

// out[b] = sigmoid(h2[b,:] @ Wout + bout); one wave per row
__global__ void output_kernel(const bf16* __restrict__ H2, const float* __restrict__ Wout,
                              const float* __restrict__ bout, float* __restrict__ out) {
  int w = threadIdx.x >> 6, l = threadIdx.x & 63;
  int row = blockIdx.x * 4 + w;
  const bf16* h = H2 + (size_t)row * 512;
  float s = 0.f;
#pragma unroll
  for (int k = 0; k < 8; ++k) {
    int kk = l + k * 64;
    s += __bfloat162float(h[kk]) * Wout[kk];
  }
#pragma unroll
  for (int off = 32; off > 0; off >>= 1) s += __shfl_down(s, off);
  if (l == 0) out[row] = sigf(s + bout[0]);
}

extern "C" void kernel_launch(void* const* d_in, const int* in_sizes, int n_in,
                              void* d_out, int out_size, void* d_ws, size_t ws_size,
                              hipStream_t stream) {
  const int* tokens = (const int*)d_in[0];
  const float* emb = (const float*)d_in[1];
  const float* W1 = (const float*)d_in[2];
  const float* U1 = (const float*)d_in[3];
  const float* b1 = (const float*)d_in[4];
  const float* W2 = (const float*)d_in[5];
  const float* U2 = (const float*)d_in[6];
  const float* b2 = (const float*)d_in[7];
  const float* Wout = (const float*)d_in[8];
  const float* bout = (const float*)d_in[9];
  float* out = (float*)d_out;
  char* ws = (char*)d_ws;

  const size_t oXP = 0;          // 80*1024*128 bf16 = 20971520
  const size_t oW1T = 20971520;  // 2048*128 bf16
  const size_t oU1T = 21495808;  // 2048*512 bf16
  const size_t oW2T = 23592960;
  const size_t oU2T = 25690112;
  const size_t oH1 = 27787264;   // 2 x 1024*512 bf16
  const size_t oH2 = 29884416;
  const size_t oC1 = 31981568;   // 1024*512 f32
  const size_t oC2 = 34078720;
  if (ws_size < 36175872) return;

  bf16* XP = (bf16*)(ws + oXP);
  bf16* W1T = (bf16*)(ws + oW1T);
  bf16* U1T = (bf16*)(ws + oU1T);
  bf16* W2T = (bf16*)(ws + oW2T);
  bf16* U2T = (bf16*)(ws + oU2T);
  bf16* H1 = (bf16*)(ws + oH1);
  bf16* H2 = (bf16*)(ws + oH2);
  float* C1 = (float*)(ws + oC1);
  float* C2 = (float*)(ws + oC2);

  hipMemsetAsync(ws + oH1, 0, 1048576, stream);  // H1 buf0
  hipMemsetAsync(ws + oH2, 0, 1048576, stream);  // H2 buf0
  hipMemsetAsync(ws + oC1, 0, 4194304, stream);  // C1 + C2

  embed_kernel<<<5120, 256, 0, stream>>>(tokens, emb, XP);
  transpose_kernel<<<dim3(64, 4), 256, 0, stream>>>(W1, W1T, 100, 128);
  transpose_kernel<<<dim3(64, 16), 256, 0, stream>>>(U1, U1T, 512, 512);
  transpose_kernel<<<dim3(64, 16), 256, 0, stream>>>(W2, W2T, 512, 512);
  transpose_kernel<<<dim3(64, 16), 256, 0, stream>>>(U2, U2T, 512, 512);

  auto mkL1 = [&](int t) {
    CellParams p;
    p.A0 = XP + (size_t)t * 131072; p.B0 = W1T; p.lda0 = 128; p.ldb0 = 128; p.nkt0 = 2;
    p.A1 = H1 + (size_t)(t & 1) * 524288; p.B1 = U1T; p.lda1 = 512; p.ldb1 = 512; p.nkt1 = 8;
    p.bias = b1; p.C = C1; p.H = H1 + (size_t)((t + 1) & 1) * 524288;
    return p;
  };
  auto mkL2 = [&](int t) {
    CellParams p;
    p.A0 = H1 + (size_t)((t + 1) & 1) * 524288; p.B0 = W2T; p.lda0 = 512; p.ldb0 = 512; p.nkt0 = 8;
    p.A1 = H2 + (size_t)(t & 1) * 524288; p.B1 = U2T; p.lda1 = 512; p.ldb1 = 512; p.nkt1 = 8;
    p.bias = b2; p.C = C2; p.H = H2 + (size_t)((t + 1) & 1) * 524288;
    return p;
  };

  cell_kernel<<<128, 512, 0, stream>>>(mkL1(0), mkL1(0));
  for (int k = 1; k < T_; ++k)
    cell_kernel<<<256, 512, 0, stream>>>(mkL2(k - 1), mkL1(k));  // layer2(k-1) || layer1(k)
  cell_kernel<<<128, 512, 0, stream>>>(mkL2(T_ - 1), mkL2(T_ - 1));

  // final h2 in buffer (T_&1)==0
  output_kernel<<<256, 256, 0, stream>>>(H2, Wout, bout, out);
}